// Round 10
// baseline (82.651 us; speedup 1.0000x reference)
//
#include <hip/hip_runtime.h>
#include <hip/hip_bf16.h>

// PGExplainer edge mask.
//  1) f12@W1 factorized: P_top = embed@W1[:64]+b1, P_bot = embed@W1[64:]
//     (LDS-tiled fp32 GEMM; k-loop unroll LIMITED to 2 — full unroll
//      spilled to scratch). rowptr + row16 duties fused as trailing blocks.
//  2) keys (col*n+row) sorted ascending (np.unique) -> argsort is identity.
//     Reverse-edge lookup via CSR rowptr + interpolation-guess + local scan
//     over row16 (u16, 3.2 MB, L2-resident).
//  3) sigmoid(log(u)-log1p(-u)+la) == u / (u + (1-u)*exp(-la)).
//  4) FULL FUSION: reverse VALUE is RECOMPUTED, not looked up. Only ~1600
//     of 1.6M edges have a reverse (keys = unique draws from 1.6e9), so the
//     matched branch is exec-masked nearly everywhere. Kills the vals16
//     array, one launch, one dependency, and the q16 quantization.
//  5) Ptop/Pbot fp8 e4m3 (2.56 MB each, L2-resident gathers; unpack via
//     cvt_pk_f32_fp8); dot in packed f32x2 (v_pk_add/max/fma).

typedef __attribute__((ext_vector_type(2))) float f32x2;

#define EPAD 68   // embed-tile row stride (floats): 16B-aligned, bank-spread

__global__ __launch_bounds__(256) void precompute_kernel(
        const float* __restrict__ embed,
        const float* __restrict__ W1,
        const float* __restrict__ b1,
        unsigned* __restrict__ Ptop,          // fp8 e4m3, 16 u32 per node
        unsigned* __restrict__ Pbot,          // fp8 e4m3, 16 u32 per node
        const int* __restrict__ col,
        const int* __restrict__ row,
        int* __restrict__ rowptr,
        unsigned short* __restrict__ row16,
        int n_nodes, int n_edges, int gemm_blocks, int rp_blocks) {
    int t = threadIdx.x;
    int bid = blockIdx.x;

    if (bid >= gemm_blocks + rp_blocks) {
        // ---- row16 duty: row16[e] = (u16)row[e], 8 edges/thread ----
        int gt = (bid - gemm_blocks - rp_blocks) * 256 + t;
        int e8 = gt * 8;
        if (e8 + 7 < n_edges) {
            int4 r0 = ((const int4*)(row + e8))[0];
            int4 r1 = ((const int4*)(row + e8))[1];
            uint4 packed;
            packed.x = (unsigned)r0.x | ((unsigned)r0.y << 16);
            packed.y = (unsigned)r0.z | ((unsigned)r0.w << 16);
            packed.z = (unsigned)r1.x | ((unsigned)r1.y << 16);
            packed.w = (unsigned)r1.z | ((unsigned)r1.w << 16);
            *(uint4*)(row16 + e8) = packed;
        } else {
            for (int e = e8; e < n_edges; ++e) row16[e] = (unsigned short)row[e];
        }
        return;
    }
    if (bid >= gemm_blocks) {
        // ---- rowptr duty: rowptr[v] = lower_bound(col, v) ----
        int v = (bid - gemm_blocks) * 256 + t;
        if (v <= n_nodes) {
            int lo = 0, hi = n_edges;
            while (lo < hi) {
                int mid = (lo + hi) >> 1;
                if (col[mid] < v) lo = mid + 1; else hi = mid;
            }
            rowptr[v] = lo;
        }
        return;
    }

    __shared__ float W1s[128 * 64];     // 32 KB
    __shared__ float E[64 * EPAD];      // 17.4 KB
    int base = bid * 64;

#pragma unroll
    for (int i = 0; i < 8; ++i) {
        int idx = i * 256 + t;
        ((float4*)W1s)[idx] = ((const float4*)W1)[idx];
    }
#pragma unroll
    for (int i = 0; i < 4; ++i) {
        int fi = i * 256 + t;
        int n = fi >> 4;
        int k4 = (fi & 15) * 4;
        float4 v;
        if (base + n < n_nodes)
            v = ((const float4*)(embed + (size_t)(base + n) * 64))[fi & 15];
        else
            v = make_float4(0.f, 0.f, 0.f, 0.f);
        *((float4*)(E + n * EPAD + k4)) = v;
    }
    __syncthreads();

    int tj = t & 15, tn = t >> 4;
    int j4 = tj * 4, n4 = tn * 4;
    float4 b1v = *(const float4*)(b1 + j4);
    float4 at[4], ab[4];
#pragma unroll
    for (int i = 0; i < 4; ++i) {
        at[i] = b1v;
        ab[i] = make_float4(0.f, 0.f, 0.f, 0.f);
    }

    // unroll 2 ONLY: full unroll hoists ~768 floats of LDS loads -> spill
#pragma unroll 2
    for (int k4 = 0; k4 < 64; k4 += 4) {
        float4 e[4], wt[4], wb[4];
#pragma unroll
        for (int i = 0; i < 4; ++i) {
            e[i]  = *(const float4*)(E + (n4 + i) * EPAD + k4);
            wt[i] = *(const float4*)(W1s + (k4 + i) * 64 + j4);
            wb[i] = *(const float4*)(W1s + (64 + k4 + i) * 64 + j4);
        }
#pragma unroll
        for (int n = 0; n < 4; ++n) {
#pragma unroll
            for (int kk = 0; kk < 4; ++kk) {
                float ev = (kk == 0) ? e[n].x : (kk == 1) ? e[n].y
                         : (kk == 2) ? e[n].z : e[n].w;
                at[n].x += ev * wt[kk].x;  at[n].y += ev * wt[kk].y;
                at[n].z += ev * wt[kk].z;  at[n].w += ev * wt[kk].w;
                ab[n].x += ev * wb[kk].x;  ab[n].y += ev * wb[kk].y;
                ab[n].z += ev * wb[kk].z;  ab[n].w += ev * wb[kk].w;
            }
        }
    }

#pragma unroll
    for (int i = 0; i < 4; ++i) {
        int node = base + n4 + i;
        if (node >= n_nodes) break;
        int wt8 = __builtin_amdgcn_cvt_pk_fp8_f32(at[i].x, at[i].y, 0, false);
        wt8     = __builtin_amdgcn_cvt_pk_fp8_f32(at[i].z, at[i].w, wt8, true);
        Ptop[(size_t)node * 16 + tj] = (unsigned)wt8;
        int wb8 = __builtin_amdgcn_cvt_pk_fp8_f32(ab[i].x, ab[i].y, 0, false);
        wb8     = __builtin_amdgcn_cvt_pk_fp8_f32(ab[i].z, ab[i].w, wb8, true);
        Pbot[(size_t)node * 16 + tj] = (unsigned)wb8;
    }
}

// 4 relu-dot terms from one fp8-quad word per side, packed f32x2 math
#define DOTW(au, bu, wp, acc0, acc1) do {                             \
    f32x2 alo = __builtin_amdgcn_cvt_pk_f32_fp8((au), false);         \
    f32x2 ahi = __builtin_amdgcn_cvt_pk_f32_fp8((au), true);          \
    f32x2 blo = __builtin_amdgcn_cvt_pk_f32_fp8((bu), false);         \
    f32x2 bhi = __builtin_amdgcn_cvt_pk_f32_fp8((bu), true);          \
    f32x2 s0 = alo + blo, s1 = ahi + bhi;                             \
    s0 = __builtin_elementwise_max(s0, (f32x2)0.f);                   \
    s1 = __builtin_elementwise_max(s1, (f32x2)0.f);                   \
    acc0 += s0 * ((const f32x2*)(wp))[0];                             \
    acc1 += s1 * ((const f32x2*)(wp))[1];                             \
} while (0)

__device__ __forceinline__ float mlp_sigmoid(const uint4* __restrict__ pt,
                                             const uint4* __restrict__ pb,
                                             const float* __restrict__ W2,
                                             float b2v, float u) {
    f32x2 acc0 = {b2v, 0.f}, acc1 = {0.f, 0.f};
    f32x2 acc2 = {0.f, 0.f}, acc3 = {0.f, 0.f};
#pragma unroll
    for (int g = 0; g < 4; ++g) {
        uint4 a = pt[g];
        uint4 b = pb[g];
        const float* w = W2 + g * 16;
        DOTW(a.x, b.x, w,      acc0, acc1);
        DOTW(a.y, b.y, w + 4,  acc2, acc3);
        DOTW(a.z, b.z, w + 8,  acc0, acc1);
        DOTW(a.w, b.w, w + 12, acc2, acc3);
    }
    f32x2 acc = (acc0 + acc1) + (acc2 + acc3);
    float la = acc.x + acc.y;
    return u / (u + (1.f - u) * __expf(-la));
}

__global__ __launch_bounds__(256) void fused_edge_kernel(
        const uint4* __restrict__ Ptop,   // fp8x16 per node
        const uint4* __restrict__ Pbot,
        const float* __restrict__ W2,
        const float* __restrict__ b2,
        const float* __restrict__ noise,
        const int* __restrict__ col,
        const int* __restrict__ row,
        const unsigned short* __restrict__ row16,
        const int* __restrict__ rowptr,
        float* __restrict__ out,
        int n_edges, float inv_n) {
    int e = blockIdx.x * blockDim.x + threadIdx.x;
    if (e >= n_edges) return;
    int c = col[e], r = row[e];
    float u = noise[e];
    float b2v = b2[0];

    // issue search-state loads early: they resolve under the MLP's VALU block
    int lo = rowptr[r], hi = rowptr[r + 1];
    bool seg = hi > lo;
    int g = 0, pr = -1;
    if (seg) {
        g = lo + (int)((float)c * (float)(hi - lo) * inv_n);
        if (g >= hi) g = hi - 1;
        pr = row16[g];
    }

    // forward value (gathers: Ptop[c] streams w/ sorted col; Pbot[r] L2)
    float v = mlp_sigmoid(Ptop + (size_t)c * 4, Pbot + (size_t)r * 4, W2, b2v, u);

    // finish the scan (lines already in L1)
    int ridx = -1;
    if (seg) {
        if (pr < c) {
            while (++g < hi) { pr = row16[g]; if (pr >= c) break; }
            if (g < hi && pr == c) ridx = g;
        } else {
            while (pr > c && g > lo) pr = row16[--g];
            if (pr == c) ridx = g;
        }
    }

    // reverse value recomputed; branch taken by ~0.1% of edges (exec-masked)
    float rev = 0.f;
    if (ridx >= 0) {
        float u2 = noise[ridx];
        rev = mlp_sigmoid(Ptop + (size_t)r * 4, Pbot + (size_t)c * 4, W2, b2v, u2);
    }
    out[e] = (v + rev) * 0.5f;
}

extern "C" void kernel_launch(void* const* d_in, const int* in_sizes, int n_in,
                              void* d_out, int out_size, void* d_ws, size_t ws_size,
                              hipStream_t stream) {
    const float* embed = (const float*)d_in[0];
    const float* W1    = (const float*)d_in[1];
    const float* b1    = (const float*)d_in[2];
    const float* W2    = (const float*)d_in[3];
    const float* b2    = (const float*)d_in[4];
    const float* noise = (const float*)d_in[5];
    const int*   col   = (const int*)d_in[6];
    const int*   row   = (const int*)d_in[7];

    int n_nodes = in_sizes[0] / 64;   // 40000
    int n_edges = in_sizes[5];        // 1600000
    float* out = (float*)d_out;

    char* ws = (char*)d_ws;
    size_t p_sz   = (size_t)n_nodes * 16 * sizeof(unsigned);   // 2.56 MB each
    size_t e16_sz = (size_t)n_edges * sizeof(unsigned short);  // 3.2 MB
    unsigned*       Ptop   = (unsigned*)ws;
    unsigned*       Pbot   = (unsigned*)(ws + p_sz);
    unsigned short* row16  = (unsigned short*)(ws + 2 * p_sz);
    int*            rowptr = (int*)(ws + 2 * p_sz + e16_sz);

    int gemm_blocks = (n_nodes + 63) / 64;
    int rp_blocks   = (n_nodes + 256) / 256;            // v in [0, n_nodes]
    int r16_blocks  = (n_edges + 2047) / 2048;          // 8 edges/thread

    precompute_kernel<<<gemm_blocks + rp_blocks + r16_blocks, 256, 0, stream>>>(
        embed, W1, b1, Ptop, Pbot, col, row, rowptr, row16,
        n_nodes, n_edges, gemm_blocks, rp_blocks);

    fused_edge_kernel<<<(n_edges + 255) / 256, 256, 0, stream>>>(
        (const uint4*)Ptop, (const uint4*)Pbot, W2, b2, noise, col, row,
        row16, rowptr, out, n_edges, 1.0f / (float)n_nodes);
}

// Round 11
// 75.643 us; speedup vs baseline: 1.0926x; 1.0926x over previous
//
#include <hip/hip_runtime.h>
#include <hip/hip_bf16.h>

// PGExplainer edge mask.  (R11 = R9 structure + 2-edge/thread edge_value;
// R10's full fusion REVERTED: union of random working sets (Ptop+Pbot+row16
// = 8.5 MB) overflowed the 4 MB per-XCD L2 -> 87 MB HBM fetch, 67 µs.)
//  1) f12@W1 factorized: P_top = embed@W1[:64]+b1, P_bot = embed@W1[64:]
//     (LDS-tiled fp32 GEMM; k-loop unroll LIMITED to 2 — full unroll
//      spilled to scratch). rowptr duty fused into trailing blocks.
//  2) keys (col*n+row) sorted ascending (np.unique) -> argsort is identity.
//     Reverse-edge lookup via CSR rowptr + interpolation-guess + local scan.
//  3) sigmoid(log(u)-log1p(-u)+la) == u / (u + (1-u)*exp(-la)).
//  4) Per-kernel random-gather footprint kept under the 4 MB per-XCD L2:
//     - edge_value: Pbot fp8 (2.56 MB random; Ptop streams w/ sorted col)
//     - symmetrize: row16 u16 (3.2 MB probes); vals16 fetched only on match
//  5) edge_value: 2 edges/thread (8 independent 16B gathers in flight),
//     packed f32x2 math; symmetrize: 4 edges/thread probe chains.

typedef __attribute__((ext_vector_type(2))) float f32x2;

#define EPAD 68   // embed-tile row stride (floats): 16B-aligned, bank-spread

__global__ __launch_bounds__(256) void precompute_kernel(
        const float* __restrict__ embed,
        const float* __restrict__ W1,
        const float* __restrict__ b1,
        unsigned* __restrict__ Ptop,          // fp8 e4m3, 16 u32 per node
        unsigned* __restrict__ Pbot,          // fp8 e4m3, 16 u32 per node
        const int* __restrict__ col,
        int* __restrict__ rowptr,
        int n_nodes, int n_edges, int gemm_blocks) {
    int t = threadIdx.x;

    if ((int)blockIdx.x >= gemm_blocks) {
        // ---- rowptr duty: rowptr[v] = lower_bound(col, v) ----
        int v = (blockIdx.x - gemm_blocks) * 256 + t;
        if (v <= n_nodes) {
            int lo = 0, hi = n_edges;
            while (lo < hi) {
                int mid = (lo + hi) >> 1;
                if (col[mid] < v) lo = mid + 1; else hi = mid;
            }
            rowptr[v] = lo;
        }
        return;
    }

    __shared__ float W1s[128 * 64];     // 32 KB
    __shared__ float E[64 * EPAD];      // 17.4 KB
    int base = blockIdx.x * 64;

#pragma unroll
    for (int i = 0; i < 8; ++i) {
        int idx = i * 256 + t;
        ((float4*)W1s)[idx] = ((const float4*)W1)[idx];
    }
#pragma unroll
    for (int i = 0; i < 4; ++i) {
        int fi = i * 256 + t;
        int n = fi >> 4;
        int k4 = (fi & 15) * 4;
        float4 v;
        if (base + n < n_nodes)
            v = ((const float4*)(embed + (size_t)(base + n) * 64))[fi & 15];
        else
            v = make_float4(0.f, 0.f, 0.f, 0.f);
        *((float4*)(E + n * EPAD + k4)) = v;
    }
    __syncthreads();

    int tj = t & 15, tn = t >> 4;
    int j4 = tj * 4, n4 = tn * 4;
    float4 b1v = *(const float4*)(b1 + j4);
    float4 at[4], ab[4];
#pragma unroll
    for (int i = 0; i < 4; ++i) {
        at[i] = b1v;
        ab[i] = make_float4(0.f, 0.f, 0.f, 0.f);
    }

    // unroll 2 ONLY: full unroll hoists ~768 floats of LDS loads -> spill
#pragma unroll 2
    for (int k4 = 0; k4 < 64; k4 += 4) {
        float4 e[4], wt[4], wb[4];
#pragma unroll
        for (int i = 0; i < 4; ++i) {
            e[i]  = *(const float4*)(E + (n4 + i) * EPAD + k4);
            wt[i] = *(const float4*)(W1s + (k4 + i) * 64 + j4);
            wb[i] = *(const float4*)(W1s + (64 + k4 + i) * 64 + j4);
        }
#pragma unroll
        for (int n = 0; n < 4; ++n) {
#pragma unroll
            for (int kk = 0; kk < 4; ++kk) {
                float ev = (kk == 0) ? e[n].x : (kk == 1) ? e[n].y
                         : (kk == 2) ? e[n].z : e[n].w;
                at[n].x += ev * wt[kk].x;  at[n].y += ev * wt[kk].y;
                at[n].z += ev * wt[kk].z;  at[n].w += ev * wt[kk].w;
                ab[n].x += ev * wb[kk].x;  ab[n].y += ev * wb[kk].y;
                ab[n].z += ev * wb[kk].z;  ab[n].w += ev * wb[kk].w;
            }
        }
    }

#pragma unroll
    for (int i = 0; i < 4; ++i) {
        int node = base + n4 + i;
        if (node >= n_nodes) break;
        int wt8 = __builtin_amdgcn_cvt_pk_fp8_f32(at[i].x, at[i].y, 0, false);
        wt8     = __builtin_amdgcn_cvt_pk_fp8_f32(at[i].z, at[i].w, wt8, true);
        Ptop[(size_t)node * 16 + tj] = (unsigned)wt8;
        int wb8 = __builtin_amdgcn_cvt_pk_fp8_f32(ab[i].x, ab[i].y, 0, false);
        wb8     = __builtin_amdgcn_cvt_pk_fp8_f32(ab[i].z, ab[i].w, wb8, true);
        Pbot[(size_t)node * 16 + tj] = (unsigned)wb8;
    }
}

// 4 relu-dot terms from one fp8-quad word per side, packed f32x2 math
#define DOTW(au, bu, wp, acc0, acc1) do {                             \
    f32x2 alo = __builtin_amdgcn_cvt_pk_f32_fp8((au), false);         \
    f32x2 ahi = __builtin_amdgcn_cvt_pk_f32_fp8((au), true);          \
    f32x2 blo = __builtin_amdgcn_cvt_pk_f32_fp8((bu), false);         \
    f32x2 bhi = __builtin_amdgcn_cvt_pk_f32_fp8((bu), true);          \
    f32x2 s0 = alo + blo, s1 = ahi + bhi;                             \
    s0 = __builtin_elementwise_max(s0, (f32x2)0.f);                   \
    s1 = __builtin_elementwise_max(s1, (f32x2)0.f);                   \
    acc0 += s0 * ((const f32x2*)(wp))[0];                             \
    acc1 += s1 * ((const f32x2*)(wp))[1];                             \
} while (0)

__global__ __launch_bounds__(256) void edge_value_kernel(
        const uint4* __restrict__ Ptop,   // fp8x16 per node
        const uint4* __restrict__ Pbot,
        const float* __restrict__ W2,
        const float* __restrict__ b2,
        const float* __restrict__ noise,
        const int* __restrict__ col,
        const int* __restrict__ row,
        unsigned short* __restrict__ row16,
        unsigned short* __restrict__ vals16,
        int n_edges) {
    int t = threadIdx.x;
    int e0 = blockIdx.x * 512 + t;
    int e1 = e0 + 256;
    if (e0 >= n_edges) return;
    bool p1 = e1 < n_edges;

    int c0 = col[e0], r0 = row[e0];
    float u0 = noise[e0];
    int c1 = 0, r1 = 0;
    float u1 = 0.f;
    if (p1) { c1 = col[e1]; r1 = row[e1]; u1 = noise[e1]; }

    const uint4* pt0 = Ptop + (size_t)c0 * 4;
    const uint4* pb0 = Pbot + (size_t)r0 * 4;
    const uint4* pt1 = Ptop + (size_t)c1 * 4;   // c1=0 if !p1: safe
    const uint4* pb1 = Pbot + (size_t)r1 * 4;

    float b2v = b2[0];
    f32x2 a00 = {b2v, 0.f}, a01 = {0.f, 0.f}, a02 = {0.f, 0.f}, a03 = {0.f, 0.f};
    f32x2 a10 = {b2v, 0.f}, a11 = {0.f, 0.f}, a12 = {0.f, 0.f}, a13 = {0.f, 0.f};
#pragma unroll
    for (int g = 0; g < 4; ++g) {
        uint4 a = pt0[g], b = pb0[g];
        uint4 x = pt1[g], y = pb1[g];
        const float* w = W2 + g * 16;
        DOTW(a.x, b.x, w,      a00, a01);
        DOTW(x.x, y.x, w,      a10, a11);
        DOTW(a.y, b.y, w + 4,  a02, a03);
        DOTW(x.y, y.y, w + 4,  a12, a13);
        DOTW(a.z, b.z, w + 8,  a00, a01);
        DOTW(x.z, y.z, w + 8,  a10, a11);
        DOTW(a.w, b.w, w + 12, a02, a03);
        DOTW(x.w, y.w, w + 12, a12, a13);
    }
    f32x2 s0 = (a00 + a01) + (a02 + a03);
    float la0 = s0.x + s0.y;
    float v0 = u0 / (u0 + (1.f - u0) * __expf(-la0));
    unsigned q0 = (unsigned)(v0 * 65535.f + 0.5f);
    if (q0 > 65535u) q0 = 65535u;
    row16[e0]  = (unsigned short)r0;
    vals16[e0] = (unsigned short)q0;

    if (p1) {
        f32x2 s1 = (a10 + a11) + (a12 + a13);
        float la1 = s1.x + s1.y;
        float v1 = u1 / (u1 + (1.f - u1) * __expf(-la1));
        unsigned q1 = (unsigned)(v1 * 65535.f + 0.5f);
        if (q1 > 65535u) q1 = 65535u;
        row16[e1]  = (unsigned short)r1;
        vals16[e1] = (unsigned short)q1;
    }
}

// returns q16 value (un-normalized) of reverse edge, or 0
__device__ __forceinline__ float rev_scan(const unsigned short* __restrict__ row16,
                                          const unsigned short* __restrict__ vals16,
                                          int c, int lo, int hi, int g, int rv) {
    if (rv < c) {
        while (++g < hi) { rv = row16[g]; if (rv >= c) break; }
        return (g < hi && rv == c) ? (float)vals16[g] : 0.f;
    } else {
        while (rv > c && g > lo) rv = row16[--g];
        return (rv == c) ? (float)vals16[g] : 0.f;
    }
}

__global__ __launch_bounds__(256) void symmetrize_kernel(
        const int* __restrict__ col,
        const unsigned short* __restrict__ row16,
        const unsigned short* __restrict__ vals16,
        const int* __restrict__ rowptr,
        float* __restrict__ out,
        int n_edges, float inv_n) {
    int t = threadIdx.x;
    int e0 = blockIdx.x * 1024 + t;
    int c[4], r[4], lo[4], hi[4], g[4], pr[4];
    float vq[4];
    bool p[4], s[4];

    // phase 1: streaming loads (4 edges)
#pragma unroll
    for (int i = 0; i < 4; ++i) {
        int e = e0 + i * 256;
        p[i] = e < n_edges;
        c[i] = 0; r[i] = 0; vq[i] = 0.f;
        if (p[i]) {
            c[i]  = col[e];
            r[i]  = row16[e];
            vq[i] = (float)vals16[e];
        }
    }
    // phase 2: rowptr pairs (random 8B in 160KB, L2-resident, 4 issued)
#pragma unroll
    for (int i = 0; i < 4; ++i) {
        lo[i] = 0; hi[i] = 0;
        if (p[i]) { lo[i] = rowptr[r[i]]; hi[i] = rowptr[r[i] + 1]; }
    }
    // phase 3: interpolation guesses + initial probes (4 issued)
#pragma unroll
    for (int i = 0; i < 4; ++i) {
        s[i] = p[i] && hi[i] > lo[i];
        g[i] = 0; pr[i] = 0;
        if (s[i]) {
            g[i] = lo[i] + (int)((float)c[i] * (float)(hi[i] - lo[i]) * inv_n);
            if (g[i] >= hi[i]) g[i] = hi[i] - 1;
            pr[i] = row16[g[i]];
        }
    }
    // phase 4: local scans (same-line L1 hits; value fetched only on match)
#pragma unroll
    for (int i = 0; i < 4; ++i) {
        if (!p[i]) continue;
        float rev = s[i] ? rev_scan(row16, vals16, c[i], lo[i], hi[i], g[i], pr[i]) : 0.f;
        out[e0 + i * 256] = (vq[i] + rev) * (0.5f / 65535.f);
    }
}

extern "C" void kernel_launch(void* const* d_in, const int* in_sizes, int n_in,
                              void* d_out, int out_size, void* d_ws, size_t ws_size,
                              hipStream_t stream) {
    const float* embed = (const float*)d_in[0];
    const float* W1    = (const float*)d_in[1];
    const float* b1    = (const float*)d_in[2];
    const float* W2    = (const float*)d_in[3];
    const float* b2    = (const float*)d_in[4];
    const float* noise = (const float*)d_in[5];
    const int*   col   = (const int*)d_in[6];
    const int*   row   = (const int*)d_in[7];

    int n_nodes = in_sizes[0] / 64;   // 40000
    int n_edges = in_sizes[5];        // 1600000
    float* out = (float*)d_out;

    char* ws = (char*)d_ws;
    size_t p_sz   = (size_t)n_nodes * 16 * sizeof(unsigned);   // 2.56 MB each
    size_t e16_sz = (size_t)n_edges * sizeof(unsigned short);  // 3.2 MB each
    unsigned*       Ptop   = (unsigned*)ws;
    unsigned*       Pbot   = (unsigned*)(ws + p_sz);
    unsigned short* row16  = (unsigned short*)(ws + 2 * p_sz);
    unsigned short* vals16 = (unsigned short*)(ws + 2 * p_sz + e16_sz);
    int*            rowptr = (int*)(ws + 2 * p_sz + 2 * e16_sz);

    int gemm_blocks = (n_nodes + 63) / 64;
    int rp_blocks   = (n_nodes + 256) / 256;   // covers v in [0, n_nodes]

    precompute_kernel<<<gemm_blocks + rp_blocks, 256, 0, stream>>>(
        embed, W1, b1, Ptop, Pbot, col, rowptr, n_nodes, n_edges, gemm_blocks);

    edge_value_kernel<<<(n_edges + 511) / 512, 256, 0, stream>>>(
        (const uint4*)Ptop, (const uint4*)Pbot, W2, b2, noise, col, row,
        row16, vals16, n_edges);

    symmetrize_kernel<<<(n_edges + 1023) / 1024, 256, 0, stream>>>(
        col, row16, vals16, rowptr, out, n_edges, 1.0f / (float)n_nodes);
}